// Round 7
// baseline (520.964 us; speedup 1.0000x reference)
//
#include <hip/hip_runtime.h>
#include <hip/hip_bf16.h>

#define Bc 8
#define Sc 2048
#define Hc 8
#define Dc 64
#define Ec 512
#define NTc 64
#define Tc (Bc*Sc)
#define N1c (4*Hc*Dc)
#define HISTc (Sc - NTc)

typedef float f32x4 __attribute__((ext_vector_type(4)));
typedef __bf16 bf16x8 __attribute__((ext_vector_type(8)));
typedef short short8 __attribute__((ext_vector_type(8)));
typedef short s4v __attribute__((ext_vector_type(4)));

__device__ __forceinline__ unsigned short f2bf(float f){
  unsigned int u = __float_as_uint(f);
  u += 0x7fffu + ((u >> 16) & 1u);
  return (unsigned short)(u >> 16);
}
__device__ __forceinline__ float bf2f(unsigned short h){
  return __uint_as_float(((unsigned int)h) << 16);
}
// packed f32x2 -> bf16x2 (v_cvt_pk_bf16_f32)
__device__ __forceinline__ unsigned int pkbf(float a, float b){
  float2 f; f.x = a; f.y = b;
  __hip_bfloat162 h = __float22bfloat162_rn(f);
  unsigned int u;
  __builtin_memcpy(&u, &h, 4);
  return u;
}
__device__ __forceinline__ s4v pk4(float a, float b, float c, float d){
  uint2 u; u.x = pkbf(a, b); u.y = pkbf(c, d);
  return __builtin_bit_cast(s4v, u);
}
__device__ __forceinline__ float silu_f(float x){
  return x * __builtin_amdgcn_rcpf(1.f + __expf(-x));
}
__device__ __forceinline__ bf16x8 ldb8(const unsigned short* p){
  return __builtin_bit_cast(bf16x8, *(const short8*)p);
}
__device__ __forceinline__ f32x4 mfma16(bf16x8 a, bf16x8 b, f32x4 c){
  return __builtin_amdgcn_mfma_f32_16x16x32_bf16(a, b, c, 0, 0, 0);
}
__device__ __forceinline__ void gl_lds16(const void* g, void* l){
  __builtin_amdgcn_global_load_lds((const __attribute__((address_space(1))) unsigned int*)g,
                                   (__attribute__((address_space(3))) unsigned int*)l, 16, 0, 0);
}
// gfx950 16-lane-group swap: a[q1]<->b[q0], a[q3]<->b[q2] (both modified in place)
__device__ __forceinline__ void pswap16(unsigned int &a, unsigned int &b){
  asm volatile("v_permlane16_swap_b32 %0, %1" : "+v"(a), "+v"(b));
}

// ---------------- transpose + cast fp32 -> bf16 : out[c][r] = in[r][c] ----------------
__global__ __launch_bounds__(1024) void k_transpose_cast(const float* __restrict__ in,
                                                         unsigned short* __restrict__ out,
                                                         int R, int C){
  __shared__ float tile[32][33];
  int tx = threadIdx.x, ty = threadIdx.y;
  int c0 = blockIdx.x * 32, r0 = blockIdx.y * 32;
  tile[ty][tx] = in[(size_t)(r0 + ty) * C + c0 + tx];
  __syncthreads();
  out[(size_t)(c0 + ty) * R + r0 + tx] = f2bf(tile[tx][ty]);
}

// ---------------- input layernorm -> bf16 (one wave per row of 512) ----------------
__global__ __launch_bounds__(256) void k_ln_in(const float* __restrict__ x, const float* __restrict__ g,
                                               const float* __restrict__ b, unsigned short* __restrict__ xn){
  int lane = threadIdx.x & 63;
  int row = blockIdx.x * 4 + (threadIdx.x >> 6);
  const float* xr = x + (size_t)row * Ec + lane * 8;
  float4 v0 = *(const float4*)xr;
  float4 v1 = *(const float4*)(xr + 4);
  float vv[8] = {v0.x, v0.y, v0.z, v0.w, v1.x, v1.y, v1.z, v1.w};
  float s = 0.f, ss = 0.f;
  #pragma unroll
  for (int j = 0; j < 8; ++j){ s += vv[j]; ss += vv[j] * vv[j]; }
  #pragma unroll
  for (int m = 1; m < 64; m <<= 1){ s += __shfl_xor(s, m); ss += __shfl_xor(ss, m); }
  float mu = s * (1.f / Ec);
  float rs = rsqrtf(ss * (1.f / Ec) - mu * mu + 1e-5f);
  int c = lane * 8;
  float o[8];
  #pragma unroll
  for (int j = 0; j < 8; ++j) o[j] = (vv[j] - mu) * rs * g[c + j] + b[c + j];
  uint4 pk; pk.x = pkbf(o[0], o[1]); pk.y = pkbf(o[2], o[3]);
  pk.z = pkbf(o[4], o[5]); pk.w = pkbf(o[6], o[7]);
  *(uint4*)(xn + (size_t)row * Ec + c) = pk;
}

// ---------------- ln(attn_out) * u -> bf16 (att and u are bf16) ----------------
__global__ __launch_bounds__(256) void k_ln_mul(const unsigned short* __restrict__ att, const float* __restrict__ g,
                                                const float* __restrict__ b, const unsigned short* __restrict__ u,
                                                unsigned short* __restrict__ par){
  int lane = threadIdx.x & 63;
  int row = blockIdx.x * 4 + (threadIdx.x >> 6);
  short8 a8 = *(const short8*)(att + (size_t)row * Ec + lane * 8);
  short8 u8 = *(const short8*)(u + (size_t)row * Ec + lane * 8);
  float vv[8];
  #pragma unroll
  for (int j = 0; j < 8; ++j) vv[j] = bf2f((unsigned short)a8[j]);
  float s = 0.f, ss = 0.f;
  #pragma unroll
  for (int j = 0; j < 8; ++j){ s += vv[j]; ss += vv[j] * vv[j]; }
  #pragma unroll
  for (int m = 1; m < 64; m <<= 1){ s += __shfl_xor(s, m); ss += __shfl_xor(ss, m); }
  float mu = s * (1.f / Ec);
  float rs = rsqrtf(ss * (1.f / Ec) - mu * mu + 1e-5f);
  int c = lane * 8;
  float o[8];
  #pragma unroll
  for (int j = 0; j < 8; ++j){
    float uu = bf2f((unsigned short)u8[j]);
    o[j] = uu * ((vv[j] - mu) * rs * g[c + j] + b[c + j]);
  }
  uint4 pk; pk.x = pkbf(o[0], o[1]); pk.y = pkbf(o[2], o[3]);
  pk.z = pkbf(o[4], o[5]); pk.w = pkbf(o[6], o[7]);
  *(uint4*)(par + (size_t)row * Ec + c) = pk;
}

// ---------------- GEMM1: 128x128 2-phase, A+B LDS dbuf, conflict-free swizzle, XCD swizzle ----------------
__global__ __launch_bounds__(256) void k_gemm_uvqk(const unsigned short* __restrict__ A,
                                                   const unsigned short* __restrict__ BT,
                                                   const float* __restrict__ bias,
                                                   unsigned short* __restrict__ u_out,
                                                   unsigned short* __restrict__ vT,
                                                   unsigned short* __restrict__ qb,
                                                   unsigned short* __restrict__ kb){
  __shared__ __align__(16) unsigned short As[2][128 * 32];
  __shared__ __align__(16) unsigned short Bs[2][128 * 32];
  int tid = threadIdx.x;
  int lane = tid & 63, w = tid >> 6;
  int lm = lane & 15, quad = lane >> 4;
  int wm = w & 1, wn = w >> 1;
  int bid = blockIdx.y * gridDim.x + blockIdx.x;       // hw linear id (x fastest)
  int id2 = (bid & 7) * 256 + (bid >> 3);              // bijective XCD swizzle, nwg=2048
  int n0 = (id2 & 15) << 7, m0 = (id2 >> 4) << 7;
  int cat = n0 >> 9;
  bool swp = (cat != 1);
  int xc = quad ^ ((lm >> 1) & 3);                     // conflict-free read chunk

  int r0s = tid >> 2, c0s = ((tid & 3) ^ ((r0s >> 1) & 3)) * 16;
  int r1s = r0s + 64;                                  // (r1s>>1)&3 == (r0s>>1)&3
  const char* saA0 = (const char*)(A  + (size_t)(m0 + r0s) * Ec) + c0s;
  const char* saA1 = (const char*)(A  + (size_t)(m0 + r1s) * Ec) + c0s;
  const char* saB0 = (const char*)(BT + (size_t)(n0 + r0s) * Ec) + c0s;
  const char* saB1 = (const char*)(BT + (size_t)(n0 + r1s) * Ec) + c0s;

  gl_lds16(saA0, (char*)As[0] + tid * 16);
  gl_lds16(saA1, (char*)As[0] + tid * 16 + 4096);
  gl_lds16(saB0, (char*)Bs[0] + tid * 16);
  gl_lds16(saB1, (char*)Bs[0] + tid * 16 + 4096);
  __syncthreads();

  f32x4 acc[4][4] = {};
  #pragma unroll 1
  for (int kt = 0; kt < 16; ++kt){
    int cur = kt & 1, nb = cur ^ 1;
    if (kt < 15){
      int k0 = (kt + 1) * 64;   // bytes
      gl_lds16(saA0 + k0, (char*)As[nb] + tid * 16);
      gl_lds16(saA1 + k0, (char*)As[nb] + tid * 16 + 4096);
      gl_lds16(saB0 + k0, (char*)Bs[nb] + tid * 16);
      gl_lds16(saB1 + k0, (char*)Bs[nb] + tid * 16 + 4096);
    }
    bf16x8 af[4], bfr[4];
    #pragma unroll
    for (int s = 0; s < 4; ++s)
      af[s]  = ldb8(As[cur] + ((wm * 64 + s * 16 + lm) * 4 + xc) * 8);
    #pragma unroll
    for (int t = 0; t < 4; ++t)
      bfr[t] = ldb8(Bs[cur] + ((wn * 64 + t * 16 + lm) * 4 + xc) * 8);
    if (swp){
      #pragma unroll
      for (int s = 0; s < 4; ++s)
        #pragma unroll
        for (int t = 0; t < 4; ++t)
          acc[s][t] = mfma16(bfr[t], af[s], acc[s][t]);
    } else {
      #pragma unroll
      for (int s = 0; s < 4; ++s)
        #pragma unroll
        for (int t = 0; t < 4; ++t)
          acc[s][t] = mfma16(af[s], bfr[t], acc[s][t]);
    }
    __syncthreads();
  }

  if (cat == 1){
    #pragma unroll
    for (int t = 0; t < 4; ++t){
      int colg = n0 + wn * 64 + t * 16 + lm;
      float bv = bias[colg];
      int c = colg & 511, h = c >> 6, d = c & 63;
      #pragma unroll
      for (int s = 0; s < 4; ++s){
        int row = m0 + wm * 64 + s * 16 + quad * 4;
        int bb_ = row >> 11, sr = row & (Sc - 1);
        s4v pv = pk4(silu_f(acc[s][t][0] + bv), silu_f(acc[s][t][1] + bv),
                     silu_f(acc[s][t][2] + bv), silu_f(acc[s][t][3] + bv));
        *(s4v*)(vT + ((size_t)(bb_ * Hc + h) * Dc + d) * Sc + sr) = pv;
      }
    }
  } else {
    #pragma unroll
    for (int s = 0; s < 4; ++s){
      int row = m0 + wm * 64 + s * 16 + lm;
      int bb_ = row >> 11, sr = row & (Sc - 1);
      #pragma unroll
      for (int t = 0; t < 4; ++t){
        int colg = n0 + wn * 64 + t * 16 + quad * 4;
        float4 bv = *(const float4*)(bias + colg);
        float v0 = silu_f(acc[s][t][0] + bv.x);
        float v1 = silu_f(acc[s][t][1] + bv.y);
        float v2 = silu_f(acc[s][t][2] + bv.z);
        float v3 = silu_f(acc[s][t][3] + bv.w);
        int c = colg & 511, h = c >> 6, d = c & 63;
        if (cat == 0){
          *(s4v*)(u_out + (size_t)row * Ec + c) = pk4(v0, v1, v2, v3);
        } else if (cat == 2){
          *(s4v*)(qb + ((size_t)(bb_ * Hc + h) * Sc + sr) * Dc + d) =
            pk4(v0 * 0.125f, v1 * 0.125f, v2 * 0.125f, v3 * 0.125f);
        } else {
          *(s4v*)(kb + ((size_t)(bb_ * Hc + h) * Sc + sr) * Dc + d) = pk4(v0, v1, v2, v3);
        }
      }
    }
  }
}

// ---------------- HSTU silu attention: barrier-free, K/V direct from L2 (no LDS) ----------------
// K/V per XCD (8 heads, via XCD swizzle) = 4MB = L2 size -> staging through LDS is pure
// overhead (catalog common-mistake #7). Each wave reads its MFMA fragments straight from
// global: K[key0+s*16+lm][quad*8(+32)] and V^T[t*16+lm][key0+(g|g+4)*8] -- index-identical
// to what the r4 swizzled-LDS reads produced. No __syncthreads anywhere; waves independent.
__global__ __launch_bounds__(256) void k_attn(const unsigned short* __restrict__ qb,
                                              const unsigned short* __restrict__ kb,
                                              const unsigned short* __restrict__ vT,
                                              unsigned short* __restrict__ att){
  int tid = threadIdx.x;
  int lane = tid & 63, w = tid >> 6;
  int lm = lane & 15, quad = lane >> 4;
  int bid = blockIdx.y * gridDim.x + blockIdx.x;   // nwg = 2048 (64 bh x 32 qblk)
  int id2 = (bid & 7) * 256 + (bid >> 3);          // XCD swizzle: XCD owns 8 bh x 32 qblk
  int bh = id2 >> 5;
  int qblk = 31 - (id2 & 31);                      // heavy blocks first (tail balance)
  int qrow = qblk * 64 + w * 16;
  int lastT = qblk;
  int ntiles = lastT + 1;

  const unsigned short* kbp = kb + (size_t)bh * Sc * Dc;
  const unsigned short* vbp = vT + (size_t)bh * Dc * Sc;
  const unsigned short* qp = qb + ((size_t)bh * Sc + qrow + lm) * Dc + quad * 8;
  bf16x8 qa0 = ldb8(qp), qa1 = ldb8(qp + 32);

  f32x4 o[4] = {};
  int qg = qrow + lm;
  int g = ((quad & 1) << 1) | (quad >> 1);         // key-slot permutation
  const unsigned short* kB  = kbp + lm * Dc + quad * 8;            // +kt*4096 +s*1024 (+32)
  const unsigned short* vB0 = vbp + (size_t)lm * Sc + g * 8;       // +t*16*Sc +kt*64
  const unsigned short* vB1 = vbp + (size_t)lm * Sc + (g + 4) * 8;

  #pragma unroll 2
  for (int kt = 0; kt < ntiles; ++kt){
    bool maskT = (kt == lastT);
    int key0 = kt * 64;
    const unsigned short* Kt = kB + kt * 4096;
    bf16x8 kf0[4], kf1[4];
    #pragma unroll
    for (int s = 0; s < 4; ++s){
      kf0[s] = ldb8(Kt + s * 1024);
      kf1[s] = ldb8(Kt + s * 1024 + 32);
    }
    unsigned int dlo[4], dhi[4];
    #pragma unroll
    for (int s = 0; s < 4; ++s){
      f32x4 sc = {0.f, 0.f, 0.f, 0.f};
      sc = mfma16(kf0[s], qa0, sc);
      sc = mfma16(kf1[s], qa1, sc);
      float p[4];
      if (maskT){
        #pragma unroll
        for (int r = 0; r < 4; ++r){
          int kg = key0 + s * 16 + quad * 4 + r;
          bool ok = (kg <= qg) && ((kg < HISTc) || (kg == qg));
          p[r] = ok ? silu_f(sc[r]) : 0.f;
        }
      } else {
        #pragma unroll
        for (int r = 0; r < 4; ++r) p[r] = silu_f(sc[r]);
      }
      dlo[s] = pkbf(p[0], p[1]);
      dhi[s] = pkbf(p[2], p[3]);
    }
    pswap16(dlo[0], dlo[1]); pswap16(dhi[0], dhi[1]);
    pswap16(dlo[2], dlo[3]); pswap16(dhi[2], dhi[3]);
    uint4 pa0u, pa1u;
    pa0u.x = dlo[0]; pa0u.y = dhi[0]; pa0u.z = dlo[1]; pa0u.w = dhi[1];
    pa1u.x = dlo[2]; pa1u.y = dhi[2]; pa1u.z = dlo[3]; pa1u.w = dhi[3];
    bf16x8 pa0 = __builtin_bit_cast(bf16x8, pa0u);
    bf16x8 pa1 = __builtin_bit_cast(bf16x8, pa1u);
    const unsigned short* Vt0 = vB0 + key0;
    const unsigned short* Vt1 = vB1 + key0;
    __builtin_amdgcn_s_setprio(1);
    #pragma unroll
    for (int t = 0; t < 4; ++t){
      bf16x8 vf0 = ldb8(Vt0 + (size_t)t * 16 * Sc);
      bf16x8 vf1 = ldb8(Vt1 + (size_t)t * 16 * Sc);
      o[t] = mfma16(pa0, vf0, o[t]);
      o[t] = mfma16(pa1, vf1, o[t]);
    }
    __builtin_amdgcn_s_setprio(0);
  }

  int bb_ = bh >> 3, hh = bh & 7;
  #pragma unroll
  for (int t = 0; t < 4; ++t){
    int d = t * 16 + lm;
    unsigned int p01 = pkbf(o[t][0] * (1.f / Sc), o[t][1] * (1.f / Sc));
    unsigned int p23 = pkbf(o[t][2] * (1.f / Sc), o[t][3] * (1.f / Sc));
    size_t base = ((size_t)(bb_ * Sc + qrow + quad * 4) * Hc + hh) * Dc + d;
    att[base]               = (unsigned short)p01;
    att[base + Hc * Dc]     = (unsigned short)(p01 >> 16);
    att[base + 2 * Hc * Dc] = (unsigned short)p23;
    att[base + 3 * Hc * Dc] = (unsigned short)(p23 >> 16);
  }
}

// ---------------- GEMM2: out = par @ w_proj + x (A+B LDS dbuf, swizzled, C^T epilogue) ----------------
__global__ __launch_bounds__(256) void k_gemm_proj(const unsigned short* __restrict__ A,
                                                   const unsigned short* __restrict__ BT,
                                                   const float* __restrict__ x,
                                                   float* __restrict__ out){
  __shared__ __align__(16) unsigned short As[2][128 * 32];
  __shared__ __align__(16) unsigned short Bs[2][128 * 32];
  int tid = threadIdx.x;
  int lane = tid & 63, w = tid >> 6;
  int lm = lane & 15, quad = lane >> 4;
  int wm = w & 1, wn = w >> 1;
  int bid = blockIdx.y * gridDim.x + blockIdx.x;       // nwg = 512
  int id2 = (bid & 7) * 64 + (bid >> 3);               // bijective XCD swizzle
  int n0 = (id2 & 3) << 7, m0 = (id2 >> 2) << 7;
  int xc = quad ^ ((lm >> 1) & 3);

  int r0s = tid >> 2, c0s = ((tid & 3) ^ ((r0s >> 1) & 3)) * 16;
  int r1s = r0s + 64;
  const char* saA0 = (const char*)(A  + (size_t)(m0 + r0s) * Ec) + c0s;
  const char* saA1 = (const char*)(A  + (size_t)(m0 + r1s) * Ec) + c0s;
  const char* saB0 = (const char*)(BT + (size_t)(n0 + r0s) * Ec) + c0s;
  const char* saB1 = (const char*)(BT + (size_t)(n0 + r1s) * Ec) + c0s;

  gl_lds16(saA0, (char*)As[0] + tid * 16);
  gl_lds16(saA1, (char*)As[0] + tid * 16 + 4096);
  gl_lds16(saB0, (char*)Bs[0] + tid * 16);
  gl_lds16(saB1, (char*)Bs[0] + tid * 16 + 4096);
  __syncthreads();

  f32x4 acc[4][4] = {};
  #pragma unroll 1
  for (int kt = 0; kt < 16; ++kt){
    int cur = kt & 1, nb = cur ^ 1;
    if (kt < 15){
      int k0 = (kt + 1) * 64;   // bytes
      gl_lds16(saA0 + k0, (char*)As[nb] + tid * 16);
      gl_lds16(saA1 + k0, (char*)As[nb] + tid * 16 + 4096);
      gl_lds16(saB0 + k0, (char*)Bs[nb] + tid * 16);
      gl_lds16(saB1 + k0, (char*)Bs[nb] + tid * 16 + 4096);
    }
    bf16x8 af[4], bfr[4];
    #pragma unroll
    for (int s = 0; s < 4; ++s)
      af[s]  = ldb8(As[cur] + ((wm * 64 + s * 16 + lm) * 4 + xc) * 8);
    #pragma unroll
    for (int t = 0; t < 4; ++t)
      bfr[t] = ldb8(Bs[cur] + ((wn * 64 + t * 16 + lm) * 4 + xc) * 8);
    #pragma unroll
    for (int s = 0; s < 4; ++s)
      #pragma unroll
      for (int t = 0; t < 4; ++t)
        acc[s][t] = mfma16(bfr[t], af[s], acc[s][t]);   // C^T orientation
    __syncthreads();
  }

  #pragma unroll
  for (int s = 0; s < 4; ++s){
    int row = m0 + wm * 64 + s * 16 + lm;
    #pragma unroll
    for (int t = 0; t < 4; ++t){
      int col = n0 + wn * 64 + t * 16 + quad * 4;
      float4 xr = *(const float4*)(x + (size_t)row * Ec + col);
      float4 o4 = {acc[s][t][0] + xr.x, acc[s][t][1] + xr.y,
                   acc[s][t][2] + xr.z, acc[s][t][3] + xr.w};
      *(float4*)(out + (size_t)row * Ec + col) = o4;
    }
  }
}

extern "C" void kernel_launch(void* const* d_in, const int* in_sizes, int n_in,
                              void* d_out, int out_size, void* d_ws, size_t ws_size,
                              hipStream_t stream){
  (void)in_sizes; (void)n_in; (void)out_size; (void)ws_size;
  const float* x        = (const float*)d_in[0];
  const float* w_uvqk   = (const float*)d_in[1];
  const float* b_uvqk   = (const float*)d_in[2];
  const float* ln_in_w  = (const float*)d_in[3];
  const float* ln_in_b  = (const float*)d_in[4];
  const float* ln_out_w = (const float*)d_in[5];
  const float* ln_out_b = (const float*)d_in[6];
  const float* w_proj   = (const float*)d_in[7];
  float* out = (float*)d_out;

  char* ws = (char*)d_ws;
  unsigned short* xn  = (unsigned short*)(ws + 0);          // 16 MB, reused as `par` later
  unsigned short* wuT = (unsigned short*)(ws + 16777216);   // 2 MB
  unsigned short* wpT = (unsigned short*)(ws + 18874368);   // 0.5 MB
  unsigned short* ub  = (unsigned short*)(ws + 19398656);   // 16 MB (bf16)
  unsigned short* qbf = (unsigned short*)(ws + 52953088);   // 16 MB
  unsigned short* kbf = (unsigned short*)(ws + 69730304);   // 16 MB
  unsigned short* vTt = (unsigned short*)(ws + 86507520);   // 16 MB
  unsigned short* att = (unsigned short*)(ws + 103284736);  // 16 MB (bf16)

  dim3 tb(32, 32);
  k_transpose_cast<<<dim3(N1c / 32, Ec / 32), tb, 0, stream>>>(w_uvqk, wuT, Ec, N1c);
  k_transpose_cast<<<dim3(Ec / 32, Ec / 32), tb, 0, stream>>>(w_proj, wpT, Ec, Ec);
  k_ln_in<<<Tc / 4, 256, 0, stream>>>(x, ln_in_w, ln_in_b, xn);
  k_gemm_uvqk<<<dim3(N1c / 128, Tc / 128), 256, 0, stream>>>(xn, wuT, b_uvqk, ub, vTt, qbf, kbf);
  k_attn<<<dim3(Bc * Hc, Sc / 64), 256, 0, stream>>>(qbf, kbf, vTt, att);
  k_ln_mul<<<Tc / 4, 256, 0, stream>>>(att, ln_out_w, ln_out_b, ub, xn);
  k_gemm_proj<<<dim3(Ec / 128, Tc / 128), 256, 0, stream>>>(xn, wpT, x, out);
}

// Round 8
// 281.954 us; speedup vs baseline: 1.8477x; 1.8477x over previous
//
#include <hip/hip_runtime.h>
#include <hip/hip_bf16.h>

#define Bc 8
#define Sc 2048
#define Hc 8
#define Dc 64
#define Ec 512
#define NTc 64
#define Tc (Bc*Sc)
#define N1c (4*Hc*Dc)
#define HISTc (Sc - NTc)

typedef float f32x4 __attribute__((ext_vector_type(4)));
typedef __bf16 bf16x8 __attribute__((ext_vector_type(8)));
typedef short short8 __attribute__((ext_vector_type(8)));
typedef short s4v __attribute__((ext_vector_type(4)));

__device__ __forceinline__ unsigned short f2bf(float f){
  unsigned int u = __float_as_uint(f);
  u += 0x7fffu + ((u >> 16) & 1u);
  return (unsigned short)(u >> 16);
}
__device__ __forceinline__ float bf2f(unsigned short h){
  return __uint_as_float(((unsigned int)h) << 16);
}
// packed f32x2 -> bf16x2 (v_cvt_pk_bf16_f32)
__device__ __forceinline__ unsigned int pkbf(float a, float b){
  float2 f; f.x = a; f.y = b;
  __hip_bfloat162 h = __float22bfloat162_rn(f);
  unsigned int u;
  __builtin_memcpy(&u, &h, 4);
  return u;
}
__device__ __forceinline__ s4v pk4(float a, float b, float c, float d){
  uint2 u; u.x = pkbf(a, b); u.y = pkbf(c, d);
  return __builtin_bit_cast(s4v, u);
}
__device__ __forceinline__ float silu_f(float x){
  return x * __builtin_amdgcn_rcpf(1.f + __expf(-x));
}
__device__ __forceinline__ bf16x8 ldb8(const unsigned short* p){
  return __builtin_bit_cast(bf16x8, *(const short8*)p);
}
__device__ __forceinline__ f32x4 mfma16(bf16x8 a, bf16x8 b, f32x4 c){
  return __builtin_amdgcn_mfma_f32_16x16x32_bf16(a, b, c, 0, 0, 0);
}
__device__ __forceinline__ void gl_lds16(const void* g, void* l){
  __builtin_amdgcn_global_load_lds((const __attribute__((address_space(1))) unsigned int*)g,
                                   (__attribute__((address_space(3))) unsigned int*)l, 16, 0, 0);
}
// gfx950 16-lane-group swap: a[q1]<->b[q0], a[q3]<->b[q2] (both modified in place)
__device__ __forceinline__ void pswap16(unsigned int &a, unsigned int &b){
  asm volatile("v_permlane16_swap_b32 %0, %1" : "+v"(a), "+v"(b));
}

// ---------------- transpose + cast fp32 -> bf16 : out[c][r] = in[r][c] ----------------
__global__ __launch_bounds__(1024) void k_transpose_cast(const float* __restrict__ in,
                                                         unsigned short* __restrict__ out,
                                                         int R, int C){
  __shared__ float tile[32][33];
  int tx = threadIdx.x, ty = threadIdx.y;
  int c0 = blockIdx.x * 32, r0 = blockIdx.y * 32;
  tile[ty][tx] = in[(size_t)(r0 + ty) * C + c0 + tx];
  __syncthreads();
  out[(size_t)(c0 + ty) * R + r0 + tx] = f2bf(tile[tx][ty]);
}

// ---------------- input layernorm -> bf16 (one wave per row of 512) ----------------
__global__ __launch_bounds__(256) void k_ln_in(const float* __restrict__ x, const float* __restrict__ g,
                                               const float* __restrict__ b, unsigned short* __restrict__ xn){
  int lane = threadIdx.x & 63;
  int row = blockIdx.x * 4 + (threadIdx.x >> 6);
  const float* xr = x + (size_t)row * Ec + lane * 8;
  float4 v0 = *(const float4*)xr;
  float4 v1 = *(const float4*)(xr + 4);
  float vv[8] = {v0.x, v0.y, v0.z, v0.w, v1.x, v1.y, v1.z, v1.w};
  float s = 0.f, ss = 0.f;
  #pragma unroll
  for (int j = 0; j < 8; ++j){ s += vv[j]; ss += vv[j] * vv[j]; }
  #pragma unroll
  for (int m = 1; m < 64; m <<= 1){ s += __shfl_xor(s, m); ss += __shfl_xor(ss, m); }
  float mu = s * (1.f / Ec);
  float rs = rsqrtf(ss * (1.f / Ec) - mu * mu + 1e-5f);
  int c = lane * 8;
  float o[8];
  #pragma unroll
  for (int j = 0; j < 8; ++j) o[j] = (vv[j] - mu) * rs * g[c + j] + b[c + j];
  uint4 pk; pk.x = pkbf(o[0], o[1]); pk.y = pkbf(o[2], o[3]);
  pk.z = pkbf(o[4], o[5]); pk.w = pkbf(o[6], o[7]);
  *(uint4*)(xn + (size_t)row * Ec + c) = pk;
}

// ---------------- ln(attn_out) * u -> bf16 (att and u are bf16) ----------------
__global__ __launch_bounds__(256) void k_ln_mul(const unsigned short* __restrict__ att, const float* __restrict__ g,
                                                const float* __restrict__ b, const unsigned short* __restrict__ u,
                                                unsigned short* __restrict__ par){
  int lane = threadIdx.x & 63;
  int row = blockIdx.x * 4 + (threadIdx.x >> 6);
  short8 a8 = *(const short8*)(att + (size_t)row * Ec + lane * 8);
  short8 u8 = *(const short8*)(u + (size_t)row * Ec + lane * 8);
  float vv[8];
  #pragma unroll
  for (int j = 0; j < 8; ++j) vv[j] = bf2f((unsigned short)a8[j]);
  float s = 0.f, ss = 0.f;
  #pragma unroll
  for (int j = 0; j < 8; ++j){ s += vv[j]; ss += vv[j] * vv[j]; }
  #pragma unroll
  for (int m = 1; m < 64; m <<= 1){ s += __shfl_xor(s, m); ss += __shfl_xor(ss, m); }
  float mu = s * (1.f / Ec);
  float rs = rsqrtf(ss * (1.f / Ec) - mu * mu + 1e-5f);
  int c = lane * 8;
  float o[8];
  #pragma unroll
  for (int j = 0; j < 8; ++j){
    float uu = bf2f((unsigned short)u8[j]);
    o[j] = uu * ((vv[j] - mu) * rs * g[c + j] + b[c + j]);
  }
  uint4 pk; pk.x = pkbf(o[0], o[1]); pk.y = pkbf(o[2], o[3]);
  pk.z = pkbf(o[4], o[5]); pk.w = pkbf(o[6], o[7]);
  *(uint4*)(par + (size_t)row * Ec + c) = pk;
}

// ---------------- GEMM1: 128x128 2-phase, A+B LDS dbuf, conflict-free swizzle, XCD swizzle ----------------
__global__ __launch_bounds__(256) void k_gemm_uvqk(const unsigned short* __restrict__ A,
                                                   const unsigned short* __restrict__ BT,
                                                   const float* __restrict__ bias,
                                                   unsigned short* __restrict__ u_out,
                                                   unsigned short* __restrict__ vT,
                                                   unsigned short* __restrict__ qb,
                                                   unsigned short* __restrict__ kb){
  __shared__ __align__(16) unsigned short As[2][128 * 32];
  __shared__ __align__(16) unsigned short Bs[2][128 * 32];
  int tid = threadIdx.x;
  int lane = tid & 63, w = tid >> 6;
  int lm = lane & 15, quad = lane >> 4;
  int wm = w & 1, wn = w >> 1;
  int bid = blockIdx.y * gridDim.x + blockIdx.x;       // hw linear id (x fastest)
  int id2 = (bid & 7) * 256 + (bid >> 3);              // bijective XCD swizzle, nwg=2048
  int n0 = (id2 & 15) << 7, m0 = (id2 >> 4) << 7;
  int cat = n0 >> 9;
  bool swp = (cat != 1);
  int xc = quad ^ ((lm >> 1) & 3);                     // conflict-free read chunk

  int r0s = tid >> 2, c0s = ((tid & 3) ^ ((r0s >> 1) & 3)) * 16;
  int r1s = r0s + 64;                                  // (r1s>>1)&3 == (r0s>>1)&3
  const char* saA0 = (const char*)(A  + (size_t)(m0 + r0s) * Ec) + c0s;
  const char* saA1 = (const char*)(A  + (size_t)(m0 + r1s) * Ec) + c0s;
  const char* saB0 = (const char*)(BT + (size_t)(n0 + r0s) * Ec) + c0s;
  const char* saB1 = (const char*)(BT + (size_t)(n0 + r1s) * Ec) + c0s;

  gl_lds16(saA0, (char*)As[0] + tid * 16);
  gl_lds16(saA1, (char*)As[0] + tid * 16 + 4096);
  gl_lds16(saB0, (char*)Bs[0] + tid * 16);
  gl_lds16(saB1, (char*)Bs[0] + tid * 16 + 4096);
  __syncthreads();

  f32x4 acc[4][4] = {};
  #pragma unroll 1
  for (int kt = 0; kt < 16; ++kt){
    int cur = kt & 1, nb = cur ^ 1;
    if (kt < 15){
      int k0 = (kt + 1) * 64;   // bytes
      gl_lds16(saA0 + k0, (char*)As[nb] + tid * 16);
      gl_lds16(saA1 + k0, (char*)As[nb] + tid * 16 + 4096);
      gl_lds16(saB0 + k0, (char*)Bs[nb] + tid * 16);
      gl_lds16(saB1 + k0, (char*)Bs[nb] + tid * 16 + 4096);
    }
    bf16x8 af[4], bfr[4];
    #pragma unroll
    for (int s = 0; s < 4; ++s)
      af[s]  = ldb8(As[cur] + ((wm * 64 + s * 16 + lm) * 4 + xc) * 8);
    #pragma unroll
    for (int t = 0; t < 4; ++t)
      bfr[t] = ldb8(Bs[cur] + ((wn * 64 + t * 16 + lm) * 4 + xc) * 8);
    if (swp){
      #pragma unroll
      for (int s = 0; s < 4; ++s)
        #pragma unroll
        for (int t = 0; t < 4; ++t)
          acc[s][t] = mfma16(bfr[t], af[s], acc[s][t]);
    } else {
      #pragma unroll
      for (int s = 0; s < 4; ++s)
        #pragma unroll
        for (int t = 0; t < 4; ++t)
          acc[s][t] = mfma16(af[s], bfr[t], acc[s][t]);
    }
    __syncthreads();
  }

  if (cat == 1){
    #pragma unroll
    for (int t = 0; t < 4; ++t){
      int colg = n0 + wn * 64 + t * 16 + lm;
      float bv = bias[colg];
      int c = colg & 511, h = c >> 6, d = c & 63;
      #pragma unroll
      for (int s = 0; s < 4; ++s){
        int row = m0 + wm * 64 + s * 16 + quad * 4;
        int bb_ = row >> 11, sr = row & (Sc - 1);
        s4v pv = pk4(silu_f(acc[s][t][0] + bv), silu_f(acc[s][t][1] + bv),
                     silu_f(acc[s][t][2] + bv), silu_f(acc[s][t][3] + bv));
        *(s4v*)(vT + ((size_t)(bb_ * Hc + h) * Dc + d) * Sc + sr) = pv;
      }
    }
  } else {
    #pragma unroll
    for (int s = 0; s < 4; ++s){
      int row = m0 + wm * 64 + s * 16 + lm;
      int bb_ = row >> 11, sr = row & (Sc - 1);
      #pragma unroll
      for (int t = 0; t < 4; ++t){
        int colg = n0 + wn * 64 + t * 16 + quad * 4;
        float4 bv = *(const float4*)(bias + colg);
        float v0 = silu_f(acc[s][t][0] + bv.x);
        float v1 = silu_f(acc[s][t][1] + bv.y);
        float v2 = silu_f(acc[s][t][2] + bv.z);
        float v3 = silu_f(acc[s][t][3] + bv.w);
        int c = colg & 511, h = c >> 6, d = c & 63;
        if (cat == 0){
          *(s4v*)(u_out + (size_t)row * Ec + c) = pk4(v0, v1, v2, v3);
        } else if (cat == 2){
          *(s4v*)(qb + ((size_t)(bb_ * Hc + h) * Sc + sr) * Dc + d) =
            pk4(v0 * 0.125f, v1 * 0.125f, v2 * 0.125f, v3 * 0.125f);
        } else {
          *(s4v*)(kb + ((size_t)(bb_ * Hc + h) * Sc + sr) * Dc + d) = pk4(v0, v1, v2, v3);
        }
      }
    }
  }
}

// ---------------- HSTU silu attention: r4 structure + balanced qblk pairing ----------------
// 1024 blocks; block handles qblk pair (31-p, p) -> exactly 33 tile-steps each. Perfect
// load balance => 4 equal blocks/CU resident full-kernel (LDS cap 5), no tail skew.
// Inner tile-step identical to r4 (best measured): swizzled DMA K/V dbuf, K=32 PV via
// permlane16_swap, setprio on PV, __syncthreads pipeline.
__global__ __launch_bounds__(256) void k_attn(const unsigned short* __restrict__ qb,
                                              const unsigned short* __restrict__ kb,
                                              const unsigned short* __restrict__ vT,
                                              unsigned short* __restrict__ att){
  __shared__ __align__(16) unsigned short Kb[2][64 * 64];
  __shared__ __align__(16) unsigned short Vb[2][64 * 64];
  int tid = threadIdx.x;
  int lane = tid & 63, w = tid >> 6;
  int lm = lane & 15, quad = lane >> 4;
  int lmx = lm & 7;
  int bid = blockIdx.y * gridDim.x + blockIdx.x;   // nwg = 1024 (64 bh x 16 pairs)
  int id2 = (bid & 7) * 128 + (bid >> 3);          // XCD swizzle: XCD owns 8 bh x 16 pairs
  int bh = id2 >> 4;
  int pr = id2 & 15;                               // pair index: qblks {31-pr, pr}

  const unsigned short* kbp = kb + (size_t)bh * Sc * Dc;
  const unsigned short* vbp = vT + (size_t)bh * Dc * Sc;

  int r0s = tid >> 3, c0s = ((tid & 7) ^ (r0s & 7)) * 16;
  int r1s = (tid + 256) >> 3, c1s = (((tid + 256) & 7) ^ (r1s & 7)) * 16;
  const char* kS0 = (const char*)kbp + (size_t)r0s * 128 + c0s;
  const char* kS1 = (const char*)kbp + (size_t)r1s * 128 + c1s;
  const char* vS0 = (const char*)vbp + (size_t)r0s * (Sc * 2) + c0s;
  const char* vS1 = (const char*)vbp + (size_t)r1s * (Sc * 2) + c1s;

  int g = ((quad & 1) << 1) | (quad >> 1);         // key-slot permutation
  int koff0 = lm * 64 + (quad ^ lmx) * 8;
  int koff1 = lm * 64 + (((quad + 4)) ^ lmx) * 8;
  int voff0 = lm * 64 + ((g ^ lmx)) * 8;
  int voff1 = lm * 64 + (((g + 4) ^ lmx)) * 8;
  int bb_ = bh >> 3, hh = bh & 7;

  #pragma unroll 1
  for (int ph = 0; ph < 2; ++ph){
    int qblk = ph ? pr : (31 - pr);
    int qrow = qblk * 64 + w * 16;
    int lastT = qblk;
    int ntiles = lastT + 1;
    int qg = qrow + lm;
    const unsigned short* qp = qb + ((size_t)bh * Sc + qrow + lm) * Dc + quad * 8;
    bf16x8 qa0 = ldb8(qp), qa1 = ldb8(qp + 32);

    { // prologue: stage tile 0 (phase-1 LDS reads all completed before prior barrier)
      gl_lds16(kS0, (char*)Kb[0] + tid * 16);
      gl_lds16(kS1, (char*)Kb[0] + tid * 16 + 4096);
      gl_lds16(vS0, (char*)Vb[0] + tid * 16);
      gl_lds16(vS1, (char*)Vb[0] + tid * 16 + 4096);
    }
    __syncthreads();

    f32x4 o[4] = {};

    auto step = [&](const unsigned short* Kc, const unsigned short* Vc,
                    char* dK, char* dV, int kt, bool do_stage){
      if (do_stage){
        gl_lds16(kS0 + (size_t)(kt + 1) * 8192, dK);
        gl_lds16(kS1 + (size_t)(kt + 1) * 8192, dK + 4096);
        gl_lds16(vS0 + (size_t)(kt + 1) * 128, dV);
        gl_lds16(vS1 + (size_t)(kt + 1) * 128, dV + 4096);
      }
      bool maskT = (kt == lastT);
      int key0 = kt * 64;
      unsigned int dlo[4], dhi[4];
      #pragma unroll
      for (int s = 0; s < 4; ++s){
        bf16x8 kf0 = ldb8(Kc + koff0 + s * 1024);
        bf16x8 kf1 = ldb8(Kc + koff1 + s * 1024);
        f32x4 sc = {0.f, 0.f, 0.f, 0.f};
        sc = mfma16(kf0, qa0, sc);
        sc = mfma16(kf1, qa1, sc);
        float p[4];
        if (maskT){
          #pragma unroll
          for (int r = 0; r < 4; ++r){
            int kg = key0 + s * 16 + quad * 4 + r;
            bool ok = (kg <= qg) && ((kg < HISTc) || (kg == qg));
            p[r] = ok ? silu_f(sc[r]) : 0.f;
          }
        } else {
          #pragma unroll
          for (int r = 0; r < 4; ++r) p[r] = silu_f(sc[r]);
        }
        dlo[s] = pkbf(p[0], p[1]);
        dhi[s] = pkbf(p[2], p[3]);
      }
      pswap16(dlo[0], dlo[1]); pswap16(dhi[0], dhi[1]);
      pswap16(dlo[2], dlo[3]); pswap16(dhi[2], dhi[3]);
      uint4 pa0u, pa1u;
      pa0u.x = dlo[0]; pa0u.y = dhi[0]; pa0u.z = dlo[1]; pa0u.w = dhi[1];
      pa1u.x = dlo[2]; pa1u.y = dhi[2]; pa1u.z = dlo[3]; pa1u.w = dhi[3];
      bf16x8 pa0 = __builtin_bit_cast(bf16x8, pa0u);
      bf16x8 pa1 = __builtin_bit_cast(bf16x8, pa1u);
      __builtin_amdgcn_s_setprio(1);
      #pragma unroll
      for (int t = 0; t < 4; ++t){
        bf16x8 vf0 = ldb8(Vc + voff0 + t * 1024);
        bf16x8 vf1 = ldb8(Vc + voff1 + t * 1024);
        o[t] = mfma16(pa0, vf0, o[t]);
        o[t] = mfma16(pa1, vf1, o[t]);
      }
      __builtin_amdgcn_s_setprio(0);
      __syncthreads();
    };

    int kt = 0;
    #pragma unroll 1
    for (; kt + 2 <= ntiles; kt += 2){
      step(Kb[0], Vb[0], (char*)Kb[1] + tid * 16, (char*)Vb[1] + tid * 16, kt, true);
      step(Kb[1], Vb[1], (char*)Kb[0] + tid * 16, (char*)Vb[0] + tid * 16, kt + 1, kt + 2 < ntiles);
    }
    if (kt < ntiles)
      step(Kb[0], Vb[0], (char*)Kb[1] + tid * 16, (char*)Vb[1] + tid * 16, kt, false);

    #pragma unroll
    for (int t = 0; t < 4; ++t){
      int d = t * 16 + lm;
      unsigned int p01 = pkbf(o[t][0] * (1.f / Sc), o[t][1] * (1.f / Sc));
      unsigned int p23 = pkbf(o[t][2] * (1.f / Sc), o[t][3] * (1.f / Sc));
      size_t base = ((size_t)(bb_ * Sc + qrow + quad * 4) * Hc + hh) * Dc + d;
      att[base]               = (unsigned short)p01;
      att[base + Hc * Dc]     = (unsigned short)(p01 >> 16);
      att[base + 2 * Hc * Dc] = (unsigned short)p23;
      att[base + 3 * Hc * Dc] = (unsigned short)(p23 >> 16);
    }
  }
}

// ---------------- GEMM2: out = par @ w_proj + x (A+B LDS dbuf, swizzled, C^T epilogue) ----------------
__global__ __launch_bounds__(256) void k_gemm_proj(const unsigned short* __restrict__ A,
                                                   const unsigned short* __restrict__ BT,
                                                   const float* __restrict__ x,
                                                   float* __restrict__ out){
  __shared__ __align__(16) unsigned short As[2][128 * 32];
  __shared__ __align__(16) unsigned short Bs[2][128 * 32];
  int tid = threadIdx.x;
  int lane = tid & 63, w = tid >> 6;
  int lm = lane & 15, quad = lane >> 4;
  int wm = w & 1, wn = w >> 1;
  int bid = blockIdx.y * gridDim.x + blockIdx.x;       // nwg = 512
  int id2 = (bid & 7) * 64 + (bid >> 3);               // bijective XCD swizzle
  int n0 = (id2 & 3) << 7, m0 = (id2 >> 2) << 7;
  int xc = quad ^ ((lm >> 1) & 3);

  int r0s = tid >> 2, c0s = ((tid & 3) ^ ((r0s >> 1) & 3)) * 16;
  int r1s = r0s + 64;
  const char* saA0 = (const char*)(A  + (size_t)(m0 + r0s) * Ec) + c0s;
  const char* saA1 = (const char*)(A  + (size_t)(m0 + r1s) * Ec) + c0s;
  const char* saB0 = (const char*)(BT + (size_t)(n0 + r0s) * Ec) + c0s;
  const char* saB1 = (const char*)(BT + (size_t)(n0 + r1s) * Ec) + c0s;

  gl_lds16(saA0, (char*)As[0] + tid * 16);
  gl_lds16(saA1, (char*)As[0] + tid * 16 + 4096);
  gl_lds16(saB0, (char*)Bs[0] + tid * 16);
  gl_lds16(saB1, (char*)Bs[0] + tid * 16 + 4096);
  __syncthreads();

  f32x4 acc[4][4] = {};
  #pragma unroll 1
  for (int kt = 0; kt < 16; ++kt){
    int cur = kt & 1, nb = cur ^ 1;
    if (kt < 15){
      int k0 = (kt + 1) * 64;   // bytes
      gl_lds16(saA0 + k0, (char*)As[nb] + tid * 16);
      gl_lds16(saA1 + k0, (char*)As[nb] + tid * 16 + 4096);
      gl_lds16(saB0 + k0, (char*)Bs[nb] + tid * 16);
      gl_lds16(saB1 + k0, (char*)Bs[nb] + tid * 16 + 4096);
    }
    bf16x8 af[4], bfr[4];
    #pragma unroll
    for (int s = 0; s < 4; ++s)
      af[s]  = ldb8(As[cur] + ((wm * 64 + s * 16 + lm) * 4 + xc) * 8);
    #pragma unroll
    for (int t = 0; t < 4; ++t)
      bfr[t] = ldb8(Bs[cur] + ((wn * 64 + t * 16 + lm) * 4 + xc) * 8);
    #pragma unroll
    for (int s = 0; s < 4; ++s)
      #pragma unroll
      for (int t = 0; t < 4; ++t)
        acc[s][t] = mfma16(bfr[t], af[s], acc[s][t]);   // C^T orientation
    __syncthreads();
  }

  #pragma unroll
  for (int s = 0; s < 4; ++s){
    int row = m0 + wm * 64 + s * 16 + lm;
    #pragma unroll
    for (int t = 0; t < 4; ++t){
      int col = n0 + wn * 64 + t * 16 + quad * 4;
      float4 xr = *(const float4*)(x + (size_t)row * Ec + col);
      float4 o4 = {acc[s][t][0] + xr.x, acc[s][t][1] + xr.y,
                   acc[s][t][2] + xr.z, acc[s][t][3] + xr.w};
      *(float4*)(out + (size_t)row * Ec + col) = o4;
    }
  }
}

extern "C" void kernel_launch(void* const* d_in, const int* in_sizes, int n_in,
                              void* d_out, int out_size, void* d_ws, size_t ws_size,
                              hipStream_t stream){
  (void)in_sizes; (void)n_in; (void)out_size; (void)ws_size;
  const float* x        = (const float*)d_in[0];
  const float* w_uvqk   = (const float*)d_in[1];
  const float* b_uvqk   = (const float*)d_in[2];
  const float* ln_in_w  = (const float*)d_in[3];
  const float* ln_in_b  = (const float*)d_in[4];
  const float* ln_out_w = (const float*)d_in[5];
  const float* ln_out_b = (const float*)d_in[6];
  const float* w_proj   = (const float*)d_in[7];
  float* out = (float*)d_out;

  char* ws = (char*)d_ws;
  unsigned short* xn  = (unsigned short*)(ws + 0);          // 16 MB, reused as `par` later
  unsigned short* wuT = (unsigned short*)(ws + 16777216);   // 2 MB
  unsigned short* wpT = (unsigned short*)(ws + 18874368);   // 0.5 MB
  unsigned short* ub  = (unsigned short*)(ws + 19398656);   // 16 MB (bf16)
  unsigned short* qbf = (unsigned short*)(ws + 52953088);   // 16 MB
  unsigned short* kbf = (unsigned short*)(ws + 69730304);   // 16 MB
  unsigned short* vTt = (unsigned short*)(ws + 86507520);   // 16 MB
  unsigned short* att = (unsigned short*)(ws + 103284736);  // 16 MB (bf16)

  dim3 tb(32, 32);
  k_transpose_cast<<<dim3(N1c / 32, Ec / 32), tb, 0, stream>>>(w_uvqk, wuT, Ec, N1c);
  k_transpose_cast<<<dim3(Ec / 32, Ec / 32), tb, 0, stream>>>(w_proj, wpT, Ec, Ec);
  k_ln_in<<<Tc / 4, 256, 0, stream>>>(x, ln_in_w, ln_in_b, xn);
  k_gemm_uvqk<<<dim3(N1c / 128, Tc / 128), 256, 0, stream>>>(xn, wuT, b_uvqk, ub, vTt, qbf, kbf);
  k_attn<<<dim3(Bc * Hc, 16), 256, 0, stream>>>(qbf, kbf, vTt, att);
  k_ln_mul<<<Tc / 4, 256, 0, stream>>>(att, ln_out_w, ln_out_b, ub, xn);
  k_gemm_proj<<<dim3(Ec / 128, Tc / 128), 256, 0, stream>>>(xn, wpT, x, out);
}